// Round 2
// baseline (112.526 us; speedup 1.0000x reference)
//
#include <hip/hip_runtime.h>
#include <math.h>

// AllPassMORR circulant conv2d, MI355X.
// x: [8,32,64,64] f32, weight: [8,36,8] f32, scale: [19] f32
// out: [8,64,64,64] f32
//
// out[b,p*8+t,ho,wo] = sum_q (-D*scale_q) / (C2 - K2*cos(phase))
//   phase = sum_s xsq[q*8+s] * |w|[p,q,(t-s)&7]
//   xsq[ci] = x[b, ci/9, ho + (ci%9)/3 - 1, wo + ci%3 - 1]^2  (zero-padded)
// where K2=2AR, C2=1+(AR)^2, D=(1-A^2)(1-R^2); the constant "1" part of the
// transfer cancels exactly because scale = concat(s,-s) sums to zero.

__global__ __launch_bounds__(512, 4)
void morr_kernel(const float* __restrict__ xg, const float* __restrict__ wg,
                 const float* __restrict__ sg, float* __restrict__ out) {
    // LDS tile: squared input, layout [c][r][cl] with cl-stride 24
    // (24 mod 32 = 24 -> row offsets {0,24,16,8} mod 32 => uniform 2-way banks, free)
    __shared__ __align__(16) float lds_x[32 * 10 * 24];   // 30720 B
    __shared__ __align__(16) float lds_w[8 * 36 * 8];     // 9216 B
    __shared__ float lds_nds[36];

    constexpr double Ad = 0.987, Rd = 0.99;
    constexpr float K2 = (float)(2.0 * Ad * Rd);
    constexpr float C2 = (float)(1.0 + (Ad * Rd) * (Ad * Rd));
    constexpr float D  = (float)((1.0 - Ad * Ad) * (1.0 - Rd * Rd));

    const int tid = threadIdx.x;
    const int b  = blockIdx.z;
    const int tr = blockIdx.y;   // 8 row-tiles of 8
    const int tc = blockIdx.x;   // 4 col-tiles of 16
    const int gr0 = tr * 8, gc0 = tc * 16;

    // ---- stage squared input tile (with zero halo) ----
    for (int i = tid; i < 32 * 10 * 18; i += 512) {
        int c = i / 180, rem = i - c * 180;
        int r = rem / 18, cl = rem - r * 18;
        int gr = gr0 - 1 + r, gc = gc0 - 1 + cl;
        float v = 0.f;
        if ((unsigned)gr < 64u && (unsigned)gc < 64u)
            v = xg[((b * 32 + c) * 64 + gr) * 64 + gc];
        lds_x[c * 240 + r * 24 + cl] = v * v;
    }
    // ---- stage |weight| ----
    for (int i = tid; i < 2304; i += 512) lds_w[i] = fabsf(wg[i]);
    // ---- stage -D*scale (differential rails, even-q branch) ----
    if (tid < 36) {
        float sv = (tid < 18) ? sg[tid] : -sg[tid - 18];
        lds_nds[tid] = -D * sv;
    }
    __syncthreads();

    // thread -> (pixel-in-tile, p-group). pgrp is wave-uniform (tid>>7).
    const int px   = tid & 127;
    const int pgrp = tid >> 7;          // handles p = {2*pgrp, 2*pgrp+1}
    const int row  = px >> 4;           // 0..7
    const int col  = px & 15;           // 0..15
    const int tb   = row * 24 + col;

    float acc[2][8];
#pragma unroll
    for (int pp = 0; pp < 2; ++pp)
#pragma unroll
        for (int t = 0; t < 8; ++t) acc[pp][t] = 0.f;

    float xq[8];
    // q = cb*9 + qq; channels cb*8 .. cb*8+7; 72 unfold elements per cb,
    // all (c,kh,kw) offsets compile-time after unroll.
    for (int cb = 0; cb < 4; ++cb) {
        const int xb = tb + cb * 1920;                 // + c*240
        const int wb = (pgrp * 2) * 288 + cb * 72;     // (p*36+q)*8 = p*288+cb*72+qq*8
        const int nb = cb * 9;
#pragma unroll
        for (int u = 0; u < 72; ++u) {
            const int cc = u / 9;            // compile-time after unroll
            const int rr = (u % 9) / 3;
            const int ww = u % 3;
            xq[u & 7] = lds_x[xb + cc * 240 + rr * 24 + ww];
            if ((u & 7) == 7) {
                const int qq = u >> 3;       // 0..8
                const float nds = lds_nds[nb + qq];
#pragma unroll
                for (int pp = 0; pp < 2; ++pp) {
                    const float4 wa = *reinterpret_cast<const float4*>(
                        &lds_w[wb + pp * 288 + qq * 8]);
                    const float4 wc = *reinterpret_cast<const float4*>(
                        &lds_w[wb + pp * 288 + qq * 8 + 4]);
                    const float wv[8] = {wa.x, wa.y, wa.z, wa.w,
                                         wc.x, wc.y, wc.z, wc.w};
#pragma unroll
                    for (int t = 0; t < 8; ++t) {
                        float ph = xq[0] * wv[t];
#pragma unroll
                        for (int s = 1; s < 8; ++s)
                            ph = fmaf(xq[s], wv[(t - s) & 7], ph);
                        float cv  = __cosf(ph);
                        float den = fmaf(-K2, cv, C2);
                        float inv = __builtin_amdgcn_rcpf(den);
                        acc[pp][t] = fmaf(nds, inv, acc[pp][t]);
                    }
                }
            }
        }
    }

    // ---- epilogue: out[b, (p*8+t), gr, gc] ----
    const int gr = gr0 + row, gc = gc0 + col;
    const int pb = pgrp * 2;
#pragma unroll
    for (int pp = 0; pp < 2; ++pp)
#pragma unroll
        for (int t = 0; t < 8; ++t) {
            const int oc = (pb + pp) * 8 + t;
            out[(b * 64 + oc) * 4096 + gr * 64 + gc] = acc[pp][t];
        }
}

extern "C" void kernel_launch(void* const* d_in, const int* in_sizes, int n_in,
                              void* d_out, int out_size, void* d_ws, size_t ws_size,
                              hipStream_t stream) {
    const float* x = (const float*)d_in[0];
    const float* w = (const float*)d_in[1];
    const float* s = (const float*)d_in[2];
    float* out = (float*)d_out;
    dim3 grid(4, 8, 8);   // (w-tiles, h-tiles, batch)
    dim3 block(512);
    hipLaunchKernelGGL(morr_kernel, grid, block, 0, stream, x, w, s, out);
}

// Round 4
// 90.527 us; speedup vs baseline: 1.2430x; 1.2430x over previous
//
#include <hip/hip_runtime.h>
#include <math.h>

// AllPassMORR circulant conv2d, MI355X.
// x: [8,32,64,64] f32, weight: [8,36,8] f32, scale: [19] f32
// out: [8,64,64,64] f32
//
// out[b,p*8+t,ho,wo] = sum_q (-D*scale_q) / (C2 - K2*cos(phase))
//   phase = sum_s xsq[q*8+s] * |w|[p,q,(t-s)&7]
//   xsq[ci] = x[b, ci/9, ho + (ci%9)/3 - 1, wo + ci%3 - 1]^2  (zero-padded)
// K2=2AR, C2=1+(AR)^2, D=(1-A^2)(1-R^2); the constant "1" part of tr cancels
// exactly because scale = concat(s,-s) sums to zero.
//
// R3: 1024-thread blocks (p split across threads, not p-pairs) -> 16 waves/CU
// instead of 8 (grid is 1 block/CU, so block size IS the occupancy).
// |w| staged pre-scaled by 1/(2pi) so phase accumulates in revolutions and
// cos is a bare v_cos_f32 (no per-element range mul).

__global__ __launch_bounds__(1024, 4)
void morr_kernel(const float* __restrict__ xg, const float* __restrict__ wg,
                 const float* __restrict__ sg, float* __restrict__ out) {
    // squared-input tile [c][r][cl], cl-stride 24 -> wave row-offsets
    // {0,24,16,8} mod 32 => uniform 2-way bank access (free)
    __shared__ __align__(16) float lds_x[32 * 10 * 24];   // 30720 B
    __shared__ __align__(16) float lds_w[8 * 36 * 8];     // 9216 B
    __shared__ float lds_nds[36];

    constexpr double Ad = 0.987, Rd = 0.99;
    constexpr float K2 = (float)(2.0 * Ad * Rd);
    constexpr float C2 = (float)(1.0 + (Ad * Rd) * (Ad * Rd));
    constexpr float D  = (float)((1.0 - Ad * Ad) * (1.0 - Rd * Rd));
    constexpr float INV2PI = 0.15915494309189535f;

    const int tid = threadIdx.x;
    const int b  = blockIdx.z;
    const int tr = blockIdx.y;   // 8 row-tiles of 8
    const int tc = blockIdx.x;   // 4 col-tiles of 16
    const int gr0 = tr * 8, gc0 = tc * 16;

    // ---- stage squared input tile (zero halo) ----
    for (int i = tid; i < 32 * 10 * 18; i += 1024) {
        int c = i / 180, rem = i - c * 180;
        int r = rem / 18, cl = rem - r * 18;
        int gr = gr0 - 1 + r, gc = gc0 - 1 + cl;
        float v = 0.f;
        if ((unsigned)gr < 64u && (unsigned)gc < 64u)
            v = xg[((b * 32 + c) * 64 + gr) * 64 + gc];
        lds_x[c * 240 + r * 24 + cl] = v * v;
    }
    // ---- stage |weight| / (2*pi)  (phase in revolutions for v_cos_f32) ----
    for (int i = tid; i < 2304; i += 1024) lds_w[i] = fabsf(wg[i]) * INV2PI;
    // ---- stage -D*scale (differential rails, even-q branch) ----
    if (tid < 36) {
        float sv = (tid < 18) ? sg[tid] : -sg[tid - 18];
        lds_nds[tid] = -D * sv;
    }
    __syncthreads();

    // thread -> (pixel-in-tile, p). p is wave-uniform (tid>>7, 2 waves per p).
    const int px  = tid & 127;
    const int p   = tid >> 7;           // 0..7
    const int row = px >> 4;            // 0..7
    const int col = px & 15;            // 0..15
    const int tb  = row * 24 + col;

    float acc[8];
#pragma unroll
    for (int t = 0; t < 8; ++t) acc[t] = 0.f;

    float xq[8];
    // q = cb*9 + qq; 72 unfold elements per cb; all offsets compile-time.
    for (int cb = 0; cb < 4; ++cb) {
        const int xb = tb + cb * 1920;             // + c*240
        const int wb = p * 288 + cb * 72;          // (p*36+q)*8
        const int nb = cb * 9;
#pragma unroll
        for (int u = 0; u < 72; ++u) {
            const int cc = u / 9;                  // compile-time after unroll
            const int rr = (u % 9) / 3;
            const int ww = u % 3;
            xq[u & 7] = lds_x[xb + cc * 240 + rr * 24 + ww];
            if ((u & 7) == 7) {
                const int qq = u >> 3;             // 0..8
                const float nds = lds_nds[nb + qq];
                const float4 wa = *reinterpret_cast<const float4*>(
                    &lds_w[wb + qq * 8]);
                const float4 wc = *reinterpret_cast<const float4*>(
                    &lds_w[wb + qq * 8 + 4]);
                const float wv[8] = {wa.x, wa.y, wa.z, wa.w,
                                     wc.x, wc.y, wc.z, wc.w};
#pragma unroll
                for (int t = 0; t < 8; ++t) {
                    float ph = xq[0] * wv[t];      // revolutions
#pragma unroll
                    for (int s = 1; s < 8; ++s)
                        ph = fmaf(xq[s], wv[(t - s) & 7], ph);
                    float cv  = __builtin_amdgcn_cosf(ph);   // cos(2*pi*ph)
                    float den = fmaf(-K2, cv, C2);
                    float inv = __builtin_amdgcn_rcpf(den);
                    acc[t] = fmaf(nds, inv, acc[t]);
                }
            }
        }
    }

    // ---- epilogue: out[b, p*8+t, gr, gc] ----
    const int gr = gr0 + row, gc = gc0 + col;
#pragma unroll
    for (int t = 0; t < 8; ++t) {
        const int oc = p * 8 + t;
        out[(b * 64 + oc) * 4096 + gr * 64 + gc] = acc[t];
    }
}

extern "C" void kernel_launch(void* const* d_in, const int* in_sizes, int n_in,
                              void* d_out, int out_size, void* d_ws, size_t ws_size,
                              hipStream_t stream) {
    const float* x = (const float*)d_in[0];
    const float* w = (const float*)d_in[1];
    const float* s = (const float*)d_in[2];
    float* out = (float*)d_out;
    dim3 grid(4, 8, 8);   // (w-tiles, h-tiles, batch)
    dim3 block(1024);
    hipLaunchKernelGGL(morr_kernel, grid, block, 0, stream, x, w, s, out);
}

// Round 5
// 90.118 us; speedup vs baseline: 1.2487x; 1.0045x over previous
//
#include <hip/hip_runtime.h>
#include <math.h>
#include <utility>

// AllPassMORR circulant conv2d, MI355X.
// x: [8,32,64,64] f32, weight: [8,36,8] f32, scale: [19] f32
// out: [8,64,64,64] f32
//
// out[b,p*8+t,ho,wo] = sum_q (-D*scale_q) / (C2 - K2*cos(2*pi*phase_rev))
//   phase_rev = sum_s xsq[q*8+s] * |w|[p,q,(t-s)&7] / (2*pi)   (w pre-scaled)
//   xsq[ci] = x[b, ci/9, ho + (ci%9)/3 - 1, wo + ci%3 - 1]^2   (zero-padded)
// K2=2AR, C2=1+(AR)^2, D=(1-A^2)(1-R^2); the constant "1" of tr cancels
// exactly because scale = concat(s,-s) sums to zero.
//
// R5: compile-time-forced unrolling (static_for). R2 counters showed
// VGPR=28 + ~2.7x VALU-cycle bloat => the 72-iter loop with u/9, u%9, u%3
// was NOT unrolled: runtime div/mod by 9/3 per element + dynamic-indexed
// arrays. Now every LDS offset is a constexpr immediate and every array
// index is static, so xq/wv/acc live in registers.

template <class F, size_t... I>
__device__ __forceinline__ void sf_impl(F&& f, std::index_sequence<I...>) {
    (f(std::integral_constant<size_t, I>{}), ...);
}
template <size_t N, class F>
__device__ __forceinline__ void static_for(F&& f) {
    sf_impl(f, std::make_index_sequence<N>{});
}

__global__ __launch_bounds__(1024, 4)
void morr_kernel(const float* __restrict__ xg, const float* __restrict__ wg,
                 const float* __restrict__ sg, float* __restrict__ out) {
    // squared-input tile [c][r][cl], cl-stride 24 -> wave row-offsets
    // {0,24,16,8} mod 32 => uniform 2-way bank access (free per m136)
    __shared__ __align__(16) float lds_x[32 * 10 * 24];   // 30720 B
    __shared__ __align__(16) float lds_w[8 * 36 * 8];     // 9216 B
    __shared__ float lds_nds[36];

    constexpr double Ad = 0.987, Rd = 0.99;
    constexpr float K2 = (float)(2.0 * Ad * Rd);
    constexpr float C2 = (float)(1.0 + (Ad * Rd) * (Ad * Rd));
    constexpr float D  = (float)((1.0 - Ad * Ad) * (1.0 - Rd * Rd));
    constexpr float INV2PI = 0.15915494309189535f;

    const int tid = threadIdx.x;
    const int b  = blockIdx.z;
    const int tr = blockIdx.y;   // 8 row-tiles of 8
    const int tc = blockIdx.x;   // 4 col-tiles of 16
    const int gr0 = tr * 8, gc0 = tc * 16;

    // ---- stage squared input tile (zero halo); runs once, cost negligible ----
    for (int i = tid; i < 32 * 10 * 18; i += 1024) {
        int c = i / 180, rem = i - c * 180;
        int r = rem / 18, cl = rem - r * 18;
        int gr = gr0 - 1 + r, gc = gc0 - 1 + cl;
        float v = 0.f;
        if ((unsigned)gr < 64u && (unsigned)gc < 64u)
            v = xg[((b * 32 + c) * 64 + gr) * 64 + gc];
        lds_x[c * 240 + r * 24 + cl] = v * v;
    }
    // ---- stage |weight|/(2*pi)  (phase in revolutions for v_cos_f32) ----
    for (int i = tid; i < 2304; i += 1024) lds_w[i] = fabsf(wg[i]) * INV2PI;
    // ---- stage -D*scale (differential rails, even-q branch) ----
    if (tid < 36) {
        float sv = (tid < 18) ? sg[tid] : -sg[tid - 18];
        lds_nds[tid] = -D * sv;
    }
    __syncthreads();

    // thread -> (pixel-in-tile, p). p is wave-uniform (tid>>7).
    const int px  = tid & 127;
    const int p   = tid >> 7;           // 0..7
    const int row = px >> 4;            // 0..7
    const int col = px & 15;            // 0..15

    const float* __restrict__ xb = &lds_x[row * 24 + col];
    const float* __restrict__ wb = &lds_w[p * 288];

    float acc[8];
    static_for<8>([&](auto T) { acc[T] = 0.f; });

    for (int cb = 0; cb < 4; ++cb) {            // runtime loop (I-cache bound)
        const float* __restrict__ xcb = xb + cb * 1920;   // + (cb*8 ch)*240
        const float* __restrict__ wcb = wb + cb * 72;     // + q*8 floats
        const float* __restrict__ ncb = &lds_nds[cb * 9];

        static_for<9>([&](auto QQ) {
            constexpr int qq = QQ;
            // xq: 8 unfold elements, constexpr LDS offsets (imm ds_read)
            float xq[8];
            static_for<8>([&](auto S) {
                constexpr int s  = S;
                constexpr int u  = qq * 8 + s;                 // 0..71 in cb
                constexpr int off = (u / 9) * 240 + ((u % 9) / 3) * 24 + (u % 3);
                xq[s] = xcb[off];
            });
            const float nds = ncb[qq];
            const float4 wa = *reinterpret_cast<const float4*>(wcb + qq * 8);
            const float4 wz = *reinterpret_cast<const float4*>(wcb + qq * 8 + 4);
            const float wv[8] = {wa.x, wa.y, wa.z, wa.w, wz.x, wz.y, wz.z, wz.w};

            static_for<8>([&](auto T) {
                constexpr int t = T;
                float ph = xq[0] * wv[t];          // revolutions
                static_for<7>([&](auto S) {
                    constexpr int s = (int)S + 1;
                    ph = fmaf(xq[s], wv[(t - s + 8) & 7], ph);
                });
                float cv  = __builtin_amdgcn_cosf(ph);   // cos(2*pi*ph)
                float den = fmaf(-K2, cv, C2);
                float inv = __builtin_amdgcn_rcpf(den);
                acc[t] = fmaf(nds, inv, acc[t]);
            });
        });
    }

    // ---- epilogue: out[b, p*8+t, gr, gc] ----
    const int gr = gr0 + row, gc = gc0 + col;
    static_for<8>([&](auto T) {
        constexpr int t = T;
        const int oc = p * 8 + t;
        out[(b * 64 + oc) * 4096 + gr * 64 + gc] = acc[t];
    });
}

extern "C" void kernel_launch(void* const* d_in, const int* in_sizes, int n_in,
                              void* d_out, int out_size, void* d_ws, size_t ws_size,
                              hipStream_t stream) {
    const float* x = (const float*)d_in[0];
    const float* w = (const float*)d_in[1];
    const float* s = (const float*)d_in[2];
    float* out = (float*)d_out;
    dim3 grid(4, 8, 8);   // (w-tiles, h-tiles, batch)
    dim3 block(1024);
    hipLaunchKernelGGL(morr_kernel, grid, block, 0, stream, x, w, s, out);
}